// Round 2
// 245.984 us; speedup vs baseline: 1.0324x; 1.0324x over previous
//
#include <hip/hip_runtime.h>

#define D_MODEL 1024
#define T_SEQ   1024
#define BATCH   8
#define NHEAD   16
#define HDIM    64

typedef float      v4f   __attribute__((ext_vector_type(4)));
typedef _Float16   half8 __attribute__((ext_vector_type(8)));
typedef _Float16   half4h __attribute__((ext_vector_type(4)));
typedef unsigned int ui4 __attribute__((ext_vector_type(4)));

// async global->LDS, 16B per lane, dest = wave-uniform base + lane*16
__device__ __forceinline__ void load_lds16(const _Float16* g, _Float16* l) {
  __builtin_amdgcn_global_load_lds(
      (const __attribute__((address_space(1))) unsigned int*)g,
      (__attribute__((address_space(3))) unsigned int*)l, 16, 0, 0);
}

// ---------------- LayerNorm (fp32 in) -> fp16 xn ----------------
__global__ __launch_bounds__(256) void ln_kernel(const float* __restrict__ x,
                                                 const float* __restrict__ gamma,
                                                 const float* __restrict__ beta,
                                                 _Float16* __restrict__ xn) {
  int row = blockIdx.x;
  int tid = threadIdx.x;
  const float* xr = x + (size_t)row * D_MODEL;
  v4f xv = *(const v4f*)(xr + tid * 4);
  float s  = xv[0] + xv[1] + xv[2] + xv[3];
  float sq = xv[0]*xv[0] + xv[1]*xv[1] + xv[2]*xv[2] + xv[3]*xv[3];
#pragma unroll
  for (int off = 32; off > 0; off >>= 1) {
    s  += __shfl_xor(s, off);
    sq += __shfl_xor(sq, off);
  }
  __shared__ float ps[4], psq[4];
  int wave = tid >> 6;
  if ((tid & 63) == 0) { ps[wave] = s; psq[wave] = sq; }
  __syncthreads();
  float tot  = ps[0] + ps[1] + ps[2] + ps[3];
  float totq = psq[0] + psq[1] + psq[2] + psq[3];
  float mean = tot * (1.0f / D_MODEL);
  float var  = totq * (1.0f / D_MODEL) - mean * mean;
  float rs   = rsqrtf(var + 1e-5f);
  v4f gv = *(const v4f*)(gamma + tid * 4);
  v4f bv = *(const v4f*)(beta + tid * 4);
  half4h o;
#pragma unroll
  for (int i = 0; i < 4; ++i)
    o[i] = (_Float16)((xv[i] - mean) * rs * gv[i] + bv[i]);
  *(half4h*)(xn + (size_t)row * D_MODEL + tid * 4) = o;
}

// ------- fragize weights: W (K x N fp32) -> Bfrag[nt][kt][lane][8] fp16 -------
// (used for the output-projection GEMM)
__global__ __launch_bounds__(256) void fragize_kernel(const float* __restrict__ W,
                                                      _Float16* __restrict__ Bf,
                                                      int N, int K) {
  int g = blockIdx.x * 256 + threadIdx.x;
  int lane = g & 63, tile = g >> 6;
  int ktiles = K >> 5;
  int kt = tile % ktiles, nt = tile / ktiles;
  int n  = nt * 16 + (lane & 15);
  int k0 = kt * 32 + (lane >> 4) * 8;
  half8 o;
#pragma unroll
  for (int j = 0; j < 8; ++j) o[j] = (_Float16)W[(size_t)(k0 + j) * N + n];
  *(half8*)(Bf + (size_t)g * 8) = o;
}

// ------- transpose weights: W (K x N fp32) -> Wt (N x K fp16) for QKV GEMM -------
__global__ __launch_bounds__(256) void wtrans_kernel(const float* __restrict__ W,
                                                     _Float16* __restrict__ Wt,
                                                     int N, int K) {
  __shared__ _Float16 t[64][72];
  int k0 = blockIdx.x * 64, n0 = blockIdx.y * 64;
  int tid = threadIdx.x;
  int r = tid >> 3, c = (tid & 7) * 8;
#pragma unroll
  for (int it = 0; it < 2; ++it) {
    int row = r + it * 32;   // k index
    const float* src = W + (size_t)(k0 + row) * N + n0 + c;
    v4f x0 = *(const v4f*)src;
    v4f x1 = *(const v4f*)(src + 4);
#pragma unroll
    for (int j = 0; j < 4; ++j) t[row][c + j] = (_Float16)x0[j];
#pragma unroll
    for (int j = 0; j < 4; ++j) t[row][c + 4 + j] = (_Float16)x1[j];
  }
  __syncthreads();
#pragma unroll
  for (int it = 0; it < 2; ++it) {
    int d = r + it * 32;     // n index
    half8 o;
#pragma unroll
    for (int j = 0; j < 8; ++j) o[j] = t[c + j][d];
    *(half8*)(Wt + (size_t)(n0 + d) * K + k0 + c) = o;
  }
}

// ------- batched transpose: Vd (P,1024,64) -> Vt (P,64,1024), fp16 -------
__global__ __launch_bounds__(256) void vtrans_kernel(const _Float16* __restrict__ Vd,
                                                     _Float16* __restrict__ Vt) {
  __shared__ _Float16 tile[64][68];
  int p  = blockIdx.y;
  int t0 = blockIdx.x * 64;
  int tid = threadIdx.x;
  int r = tid >> 3, c = (tid & 7) * 8;
#pragma unroll
  for (int it = 0; it < 2; ++it) {
    int rr = r + it * 32;
    *(ui4*)&tile[rr][c] = *(const ui4*)&Vd[((size_t)p * T_SEQ + t0 + rr) * HDIM + c];
  }
  __syncthreads();
#pragma unroll
  for (int it = 0; it < 2; ++it) {
    int d = r + it * 32;
    half8 o;
#pragma unroll
    for (int j = 0; j < 8; ++j) o[j] = tile[c + j][d];
    *(half8*)&Vt[((size_t)p * HDIM + d) * T_SEQ + t0 + c] = o;
  }
}

// ============ 128x256 8-phase QKV GEMM (T2+T3+T4+T5), 96KB static LDS ============
// A[M=8192][K=1024] fp16 (xn), Bt[N=3072][K] fp16. Grid 64x12 = 768 blocks = 3.0
// rounds of 256 CUs (balanced). 8 waves (2M x 4N), wave tile 64x64, acc 4x4.
// LDS buffer = A(128x64: 16KB) | B(256x64: 32KB); two buffers = 96KB.
// Swizzle: 16B-chunk slot ^= (row&7) on both staging source and ds_read -> each
// b128 wave read spreads 8 lanes/bank (optimal). Counted vmcnt(2) at PH4/PH8 only.

#define BAR   __builtin_amdgcn_s_barrier()
#define LGKM0 asm volatile("s_waitcnt lgkmcnt(0)" ::: "memory")
#define VMC2  asm volatile("s_waitcnt vmcnt(2)" ::: "memory")
#define PRIO1 __builtin_amdgcn_s_setprio(1)
#define PRIO0 __builtin_amdgcn_s_setprio(0)

// A-frag reads: 4 rows-of-16 covering wave's 64 M-rows, kk half KK
#define RDA(dst, BUF, KK)                                                       \
  _Pragma("unroll")                                                             \
  for (int d2 = 0; d2 < 4; ++d2)                                                \
    dst[d2] = *(const half8*)(lds + (BUF) +                                     \
                              (wm + d2 * 16 + l15) * 64 +                       \
                              ((((KK) * 4 + quad) ^ swz) * 8));

// B-frag reads: 2 cols-of-16 starting at NI0, kk half KK
#define RDB(dst, BUF, NI0, KK)                                                  \
  _Pragma("unroll")                                                             \
  for (int n2 = 0; n2 < 2; ++n2)                                                \
    dst[n2] = *(const half8*)(lds + (BUF) + 8192 +                              \
                              (wn + ((NI0) + n2) * 16 + l15) * 64 +             \
                              ((((KK) * 4 + quad) ^ swz) * 8));

// 8-MFMA cluster: acc[mi][NI0..NI0+1] += a x b
#define MFQ(A_, B_, NI0)                                                        \
  _Pragma("unroll")                                                             \
  for (int mi = 0; mi < 4; ++mi)                                                \
    _Pragma("unroll")                                                           \
    for (int n2 = 0; n2 < 2; ++n2)                                              \
      acc[mi][(NI0) + n2] = __builtin_amdgcn_mfma_f32_16x16x32_f16(             \
          A_[mi], B_[n2], acc[mi][(NI0) + n2], 0, 0, 0);

// one 8KB stage call (64 rows x 64 halves), src pre-offset by (ric*K + swz chunk)
#define STGA(BUF, R0, KT)                                                       \
  load_lds16(Asrc + (size_t)(R0) * 1024 + (KT) * 64, ldst + (BUF) + (R0) * 64)
#define STGB(BUF, R0, KT)                                                       \
  load_lds16(Bsrc + (size_t)(R0) * 1024 + (KT) * 64, ldst + (BUF) + 8192 + (R0) * 64)

__global__ __launch_bounds__(512, 2) void gemm256_qkv(
    const _Float16* __restrict__ A, const _Float16* __restrict__ Bt,
    const float* __restrict__ bias,
    _Float16* __restrict__ Qd, _Float16* __restrict__ Kd, _Float16* __restrict__ Vd) {
  __shared__ _Float16 lds[49152];   // 96 KB static
  const int K = 1024;
  int tid  = threadIdx.x;
  int wave = tid >> 6, lane = tid & 63;
  int l15  = lane & 15, quad = lane >> 4;
  int wm = (wave & 1) * 64, wn = (wave >> 1) * 64;
  int m0 = blockIdx.x * 128, n0 = blockIdx.y * 256;
  int swz = l15 & 7;

  // staging: thread covers row ric (0..63 within call), LDS slot tid&7 holds
  // global chunk (tid&7)^(ric&7)  => LDS[row][s] = G[row][s^(row&7)]
  int ric = tid >> 3;
  int colofs = ((tid & 7) ^ (ric & 7)) * 8;
  const _Float16* Asrc = A  + (size_t)(m0 + ric) * K + colofs;
  const _Float16* Bsrc = Bt + (size_t)(n0 + ric) * K + colofs;
  _Float16* ldst = lds + wave * 512;   // + lane*16B by HW

  const int B0 = 0, B1 = 24576;
  v4f acc[4][4];
  v4f zero = {0.f, 0.f, 0.f, 0.f};
#pragma unroll
  for (int i = 0; i < 4; ++i)
#pragma unroll
    for (int j = 0; j < 4; ++j) acc[i][j] = zero;

  // prologue: tile0 -> buf0 (A2+B4), tile1 A -> buf1; drain buf0 (leave 2)
  STGA(B0, 0, 0); STGA(B0, 64, 0);
  STGB(B0, 0, 0); STGB(B0, 64, 0); STGB(B0, 128, 0); STGB(B0, 192, 0);
  STGA(B1, 0, 1); STGA(B1, 64, 1);
  VMC2; BAR;

  half8 a0[4], a1[4], bl[2], bh[2];
#pragma unroll 1
  for (int i = 0; i < 8; ++i) {
    int kt1 = 2 * i + 1;
    int kt2 = (2 * i + 2 < 16) ? 2 * i + 2 : 15;  // clamped: garbage never read
    int kt3 = (2 * i + 3 < 16) ? 2 * i + 3 : 15;
    // ---------------- tile 2i in buf0 ----------------
    // PH1: kk0, ni 0-1 | stage buf1-B lo
    RDA(a0, B0, 0); RDB(bl, B0, 0, 0);
    STGB(B1, 0, kt1); STGB(B1, 64, kt1);
    BAR; LGKM0; PRIO1; MFQ(a0, bl, 0); PRIO0; BAR;
    // PH2: kk0, ni 2-3 | stage buf1-B hi
    RDB(bh, B0, 2, 0);
    STGB(B1, 128, kt1); STGB(B1, 192, kt1);
    BAR; LGKM0; PRIO1; MFQ(a0, bh, 2); PRIO0; BAR;
    // PH3: kk1, ni 0-1 | no stage
    RDA(a1, B0, 1); RDB(bl, B0, 0, 1);
    BAR; LGKM0; PRIO1; MFQ(a1, bl, 0); PRIO0; BAR;
    // PH4: kk1, ni 2-3 | stage buf0-A (tile 2i+2); counted wait -> buf1 ready
    RDB(bh, B0, 2, 1);
    STGA(B0, 0, kt2); STGA(B0, 64, kt2);
    VMC2; BAR; LGKM0; PRIO1; MFQ(a1, bh, 2); PRIO0; BAR;
    // ---------------- tile 2i+1 in buf1 ----------------
    // PH5 | stage buf0-B lo (tile 2i+2)
    RDA(a0, B1, 0); RDB(bl, B1, 0, 0);
    STGB(B0, 0, kt2); STGB(B0, 64, kt2);
    BAR; LGKM0; PRIO1; MFQ(a0, bl, 0); PRIO0; BAR;
    // PH6 | stage buf0-B hi
    RDB(bh, B1, 2, 0);
    STGB(B0, 128, kt2); STGB(B0, 192, kt2);
    BAR; LGKM0; PRIO1; MFQ(a0, bh, 2); PRIO0; BAR;
    // PH7 | no stage
    RDA(a1, B1, 1); RDB(bl, B1, 0, 1);
    BAR; LGKM0; PRIO1; MFQ(a1, bl, 0); PRIO0; BAR;
    // PH8 | stage buf1-A (tile 2i+3); counted wait -> buf0 (tile 2i+2) ready
    RDB(bh, B1, 2, 1);
    STGA(B1, 0, kt3); STGA(B1, 64, kt3);
    VMC2; BAR; LGKM0; PRIO1; MFQ(a1, bh, 2); PRIO0; BAR;
  }

  // epilogue: C row = m0+wm+mi*16+quad*4+r, col = n0+wn+ni*16+l15
  float bv[4];
#pragma unroll
  for (int ni = 0; ni < 4; ++ni) bv[ni] = bias[n0 + wn + ni * 16 + l15];
  int sec = n0 >> 10;   // 0=Q, 1=K, 2=V (BN=256 never straddles a section)
  _Float16* dstP = sec == 0 ? Qd : (sec == 1 ? Kd : Vd);
  float scale = sec == 0 ? 0.18033688f : 1.0f;   // 0.125*log2(e): softmax in exp2 domain
#pragma unroll
  for (int mi = 0; mi < 4; ++mi)
#pragma unroll
    for (int ni = 0; ni < 4; ++ni) {
      int n = n0 + wn + ni * 16 + l15;
      int h = (n >> 6) & 15, d = n & 63;
#pragma unroll
      for (int r = 0; r < 4; ++r) {
        int m = m0 + wm + mi * 16 + quad * 4 + r;
        int b = m >> 10, t = m & 1023;
        float v = acc[mi][ni][r] + bv[ni];
        dstP[((size_t)(b * NHEAD + h) * T_SEQ + t) * HDIM + d] = (_Float16)(v * scale);
      }
    }
}

// -- 128x128 MFMA GEMM (output projection): A dbuf-staged in LDS, B-frags from L2 --
template <int MODE>
__global__ __launch_bounds__(256) void gemm_kernel(
    const _Float16* __restrict__ A, const _Float16* __restrict__ Bfrag,
    const float* __restrict__ bias, int M, int N, int K,
    float* __restrict__ outF,
    _Float16* __restrict__ Qd, _Float16* __restrict__ Kd, _Float16* __restrict__ Vd) {
  __shared__ _Float16 As[2][128 * 32];   // 16 KB, double-buffered A
  int tid = threadIdx.x;
  int wave = tid >> 6, lane = tid & 63;
  int l15 = lane & 15, quad = lane >> 4;
  int wm = (wave & 1) * 64, wn = (wave >> 1) * 64;
  int m0 = blockIdx.x * 128, n0 = blockIdx.y * 128;
  v4f zero = {0.f, 0.f, 0.f, 0.f};
  v4f acc[4][4];
#pragma unroll
  for (int i = 0; i < 4; ++i)
#pragma unroll
    for (int j = 0; j < 4; ++j) acc[i][j] = zero;

  int ar0 = tid >> 2;
  int akc = (tid & 3) * 8;
  const _Float16* Ap = A + (size_t)(m0 + ar0) * K + akc;
  _Float16* AsW0 = &As[0][0] + wave * 512;
  _Float16* AsW1 = &As[1][0] + wave * 512;
  const int ktiles = K >> 5;
  const _Float16* Bp = Bfrag + (size_t)((n0 + wn) >> 4) * ktiles * 512 + lane * 8;

  load_lds16(Ap, AsW0);
  load_lds16(Ap + (size_t)64 * K, AsW0 + 2048);
  for (int kt = 0; kt < ktiles; ++kt) {
    int cur = kt & 1;
    __syncthreads();
    if (kt + 1 < ktiles) {
      _Float16* nx = cur ? AsW0 : AsW1;
      load_lds16(Ap + (kt + 1) * 32,                  nx);
      load_lds16(Ap + (kt + 1) * 32 + (size_t)64 * K, nx + 2048);
    }
    half8 bf[4];
#pragma unroll
    for (int ni = 0; ni < 4; ++ni)
      bf[ni] = *(const half8*)(Bp + ((size_t)ni * ktiles + kt) * 512);
    half8 af[4];
#pragma unroll
    for (int i = 0; i < 4; ++i)
      af[i] = *(const half8*)&As[cur][(wm + i * 16 + l15) * 32 + quad * 8];
#pragma unroll
    for (int mi = 0; mi < 4; ++mi)
#pragma unroll
      for (int ni = 0; ni < 4; ++ni)
        acc[mi][ni] = __builtin_amdgcn_mfma_f32_16x16x32_f16(af[mi], bf[ni], acc[mi][ni], 0, 0, 0);
  }
  float bv[4];
#pragma unroll
  for (int ni = 0; ni < 4; ++ni) bv[ni] = bias[n0 + wn + ni * 16 + l15];
#pragma unroll
  for (int mi = 0; mi < 4; ++mi) {
#pragma unroll
    for (int ni = 0; ni < 4; ++ni) {
      int n = n0 + wn + ni * 16 + l15;
#pragma unroll
      for (int r = 0; r < 4; ++r) {
        int m = m0 + wm + mi * 16 + quad * 4 + r;
        float v = acc[mi][ni][r] + bv[ni];
        if (MODE == 1) {
          outF[(size_t)m * N + n] = v;
        } else {
          int b = m >> 10, t = m & 1023;
          int h = (n >> 6) & 15, d = n & 63;
          size_t idx = ((size_t)(b * NHEAD + h) * T_SEQ + t) * HDIM + d;
          if (n < 1024)        Qd[idx] = (_Float16)(v * 0.18033688f);
          else if (n < 2048)   Kd[idx] = (_Float16)v;
          else                 Vd[idx] = (_Float16)v;
        }
      }
    }
  }
}

// ------- flash attention, S^T formulation: 64 q-rows/block (4 waves), 64-key tiles ------
__global__ __launch_bounds__(256) void attn_kernel(const _Float16* __restrict__ Qg,
                                                   const _Float16* __restrict__ Kk,
                                                   const _Float16* __restrict__ Vt,
                                                   const int* __restrict__ x_lens,
                                                   _Float16* __restrict__ att) {
  __shared__ _Float16 Ks[2][64 * 32];
  __shared__ _Float16 Vs[2][64 * 32];
  __shared__ _Float16 Pb[4][16 * 72];
  int blk = blockIdx.x;
  int qt = blk >> 7;
  int bh = blk & 127;
  int h  = bh & 15;
  int b  = bh >> 4;
  int t0 = qt * 64;
  int len = x_lens[b];
  int tid = threadIdx.x;
  int wave = tid >> 6, lane = tid & 63;
  int l15 = lane & 15, quad = lane >> 4;
  size_t plane = (size_t)(b * NHEAD + h) * (T_SEQ * HDIM);
  int qrow = t0 + wave * 16;
  int qabs = qrow + l15;
  const _Float16* Qp = Qg + plane + (size_t)qabs * HDIM + quad * 8;
  half8 qf0 = *(const half8*)Qp;
  half8 qf1 = *(const half8*)(Qp + 32);
  v4f zero = {0.f, 0.f, 0.f, 0.f};
  float m_i = -1e30f, l_i = 0.f;
  v4f Ov[4];
#pragma unroll
  for (int nt = 0; nt < 4; ++nt) Ov[nt] = zero;

  int jmaxb = min(t0 + 63, len - 1);
  int ntile = (jmaxb >> 6) + 1;
  int wjmax = min(qrow + 15, len - 1);

  const _Float16* src[4];
  _Float16* dst[4];
  int strd[4];
#pragma unroll
  for (int i = 0; i < 4; ++i) {
    int u = wave * 4 + i;
    int q = u & 3, hf = (u >> 2) & 1;
    if (u < 8) {
      src[i] = Kk + plane + (size_t)(q * 16 + (lane >> 2)) * HDIM + hf * 32 + (lane & 3) * 8;
      dst[i] = &Ks[hf][0] + q * 512;
      strd[i] = 64 * HDIM;
    } else {
      src[i] = Vt + plane + (size_t)(q * 16 + (lane >> 2)) * T_SEQ + hf * 32 + (lane & 3) * 8;
      dst[i] = &Vs[hf][0] + q * 512;
      strd[i] = 64;
    }
  }

  for (int jt = 0; jt < ntile; ++jt) {
    int j0 = jt * 64;
    __syncthreads();
#pragma unroll
    for (int i = 0; i < 4; ++i) {
      load_lds16(src[i], dst[i]);
      src[i] += strd[i];
    }
    __syncthreads();
    if (j0 <= wjmax) {
      v4f s[4];
#pragma unroll
      for (int nt = 0; nt < 4; ++nt) {
        s[nt] = zero;
        half8 k0 = *(const half8*)&Ks[0][(nt * 16 + l15) * 32 + quad * 8];
        half8 k1 = *(const half8*)&Ks[1][(nt * 16 + l15) * 32 + quad * 8];
        s[nt] = __builtin_amdgcn_mfma_f32_16x16x32_f16(k0, qf0, s[nt], 0, 0, 0);
        s[nt] = __builtin_amdgcn_mfma_f32_16x16x32_f16(k1, qf1, s[nt], 0, 0, 0);
      }
      float mnew = m_i;
      bool full = (j0 + 63 <= qrow) && (j0 + 63 < len);
      if (full) {
#pragma unroll
        for (int nt = 0; nt < 4; ++nt)
#pragma unroll
          for (int r = 0; r < 4; ++r)
            mnew = fmaxf(mnew, s[nt][r]);
      } else {
#pragma unroll
        for (int nt = 0; nt < 4; ++nt) {
#pragma unroll
          for (int r = 0; r < 4; ++r) {
            int key = j0 + nt * 16 + quad * 4 + r;
            float v = (key <= qabs && key < len) ? s[nt][r] : -1e30f;
            s[nt][r] = v;
            mnew = fmaxf(mnew, v);
          }
        }
      }
      mnew = fmaxf(mnew, __shfl_xor(mnew, 16));
      mnew = fmaxf(mnew, __shfl_xor(mnew, 32));
      float alpha = exp2f(m_i - mnew);
      m_i = mnew;
      float rsum = 0.f;
#pragma unroll
      for (int nt = 0; nt < 4; ++nt)
#pragma unroll
        for (int r = 0; r < 4; ++r) {
          float p = exp2f(s[nt][r] - mnew);
          s[nt][r] = p;
          rsum += p;
        }
      rsum += __shfl_xor(rsum, 16);
      rsum += __shfl_xor(rsum, 32);
      l_i = l_i * alpha + rsum;
#pragma unroll
      for (int nt = 0; nt < 4; ++nt)
#pragma unroll
        for (int r = 0; r < 4; ++r) Ov[nt][r] *= alpha;
#pragma unroll
      for (int nt = 0; nt < 4; ++nt) {
        half4h pk;
#pragma unroll
        for (int r = 0; r < 4; ++r) pk[r] = (_Float16)s[nt][r];
        *(half4h*)&Pb[wave][l15 * 72 + nt * 16 + quad * 4] = pk;
      }
      asm volatile("s_waitcnt lgkmcnt(0)" ::: "memory");
      half8 pf0 = *(const half8*)&Pb[wave][l15 * 72 + quad * 8];
      half8 pf1 = *(const half8*)&Pb[wave][l15 * 72 + 32 + quad * 8];
#pragma unroll
      for (int nt = 0; nt < 4; ++nt) {
        half8 v0 = *(const half8*)&Vs[0][(nt * 16 + l15) * 32 + quad * 8];
        half8 v1 = *(const half8*)&Vs[1][(nt * 16 + l15) * 32 + quad * 8];
        Ov[nt] = __builtin_amdgcn_mfma_f32_16x16x32_f16(v0, pf0, Ov[nt], 0, 0, 0);
        Ov[nt] = __builtin_amdgcn_mfma_f32_16x16x32_f16(v1, pf1, Ov[nt], 0, 0, 0);
      }
    }
  }
  float inv = 1.0f / l_i;
#pragma unroll
  for (int nt = 0; nt < 4; ++nt) {
    half4h ok;
#pragma unroll
    for (int r = 0; r < 4; ++r) ok[r] = (_Float16)(Ov[nt][r] * inv);
    *(half4h*)&Pb[wave][l15 * 72 + nt * 16 + quad * 4] = ok;
  }
  asm volatile("s_waitcnt lgkmcnt(0)" ::: "memory");
  int r0 = lane >> 3, c0 = (lane & 7) * 8;
  half8 o0 = *(const half8*)&Pb[wave][r0 * 72 + c0];
  half8 o1 = *(const half8*)&Pb[wave][(r0 + 8) * 72 + c0];
  *(half8*)&att[((size_t)(b * T_SEQ) + qrow + r0) * D_MODEL + h * HDIM + c0] = o0;
  *(half8*)&att[((size_t)(b * T_SEQ) + qrow + r0 + 8) * D_MODEL + h * HDIM + c0] = o1;
}

extern "C" void kernel_launch(void* const* d_in, const int* in_sizes, int n_in,
                              void* d_out, int out_size, void* d_ws, size_t ws_size,
                              hipStream_t stream) {
  const float* x        = (const float*)d_in[0];
  const int*   x_lens   = (const int*)d_in[1];
  const float* ln_gamma = (const float*)d_in[2];
  const float* ln_beta  = (const float*)d_in[3];
  const float* w_qkv    = (const float*)d_in[4];
  const float* b_qkv    = (const float*)d_in[5];
  const float* w_out    = (const float*)d_in[6];
  const float* b_out    = (const float*)d_in[7];
  float* out = (float*)d_out;

  char* w = (char*)d_ws;
  _Float16* xn    = (_Float16*)w; w += (size_t)8192 * 1024 * 2;   // aliased by Vt after gemm256
  _Float16* WtQKV = (_Float16*)w; w += (size_t)3072 * 1024 * 2;
  _Float16* BfOut = (_Float16*)w; w += (size_t)1024 * 1024 * 2;
  _Float16* Qd    = (_Float16*)w; w += (size_t)8192 * 1024 * 2;
  _Float16* Kd    = (_Float16*)w; w += (size_t)8192 * 1024 * 2;
  _Float16* Vd    = (_Float16*)w; w += (size_t)8192 * 1024 * 2;
  _Float16* att   = (_Float16*)w; w += (size_t)8192 * 1024 * 2;
  _Float16* Vt    = xn;   // xn dead after gemm256

  wtrans_kernel<<<dim3(16, 48), 256, 0, stream>>>(w_qkv, WtQKV, 3072, 1024);
  fragize_kernel<<<(1024 * 1024 / 8) / 256, 256, 0, stream>>>(w_out, BfOut, 1024, 1024);
  ln_kernel<<<8192, 256, 0, stream>>>(x, ln_gamma, ln_beta, xn);
  gemm256_qkv<<<dim3(64, 12), 512, 0, stream>>>(xn, WtQKV, b_qkv, Qd, Kd, Vd);
  vtrans_kernel<<<dim3(16, 128), 256, 0, stream>>>(Vd, Vt);
  attn_kernel<<<2048, 256, 0, stream>>>(Qd, Kd, Vt, x_lens, att);
  gemm_kernel<1><<<dim3(8192 / 128, 1024 / 128), 256, 0, stream>>>(
      att, BfOut, b_out, 8192, 1024, 1024, out, nullptr, nullptr, nullptr);
}